// Round 13
// baseline (210.208 us; speedup 1.0000x reference)
//
#include <hip/hip_runtime.h>
#include <math.h>

// Problem constants
constexpr int Bb  = 8;
constexpr int Tt  = 8;
constexpr int Ll  = 197;
constexpr int Ee  = 768;
constexpr int Hh  = 12;
constexpr int QSs = 16;
constexpr int Cc  = 64;   // Ee / Hh
constexpr int MX    = Bb * Tt * Ll;        // 12608 rows of x
constexpr int MS    = Bb * QSs;            // 128 rows of s
constexpr int MTE   = Tt;                  // 8 rows of te
constexpr int MPAD  = 12800;               // 50 * 256
constexpr int KkP = 224;                   // 14*16 k-pad for attn

using f32x4 = __attribute__((ext_vector_type(4))) float;
using s16x8 = __attribute__((ext_vector_type(8))) short;
using s16x4 = __attribute__((ext_vector_type(4))) short;

__device__ __forceinline__ unsigned short f2bf(float f) {
    unsigned int u = __float_as_uint(f);
    u = (u + 0x7fffu + ((u >> 16) & 1u)) >> 16;
    return (unsigned short)u;
}

// ---------------------------------------------------------------------------
// Fused f32 -> bf16 converts: [x | s | te | zeros] into xb (MPAD rows),
// plus in_proj_weight and out_w. One launch.
// ---------------------------------------------------------------------------
__global__ __launch_bounds__(256) void convert_all(
    const float* __restrict__ x, const float* __restrict__ s,
    const float* __restrict__ te, const float* __restrict__ ipw,
    const float* __restrict__ ow, unsigned short* __restrict__ xb,
    unsigned short* __restrict__ wb, unsigned short* __restrict__ owb)
{
    const long oX  = (long)MX * Ee;
    const long oS  = oX + (long)MS * Ee;
    const long oTe = oS + (long)MTE * Ee;
    const long nXp = (long)MPAD * Ee;
    const long nW  = (long)3 * Ee * Ee;
    const long nOW = (long)Ee * Ee;
    const long i4 = ((long)blockIdx.x * 256 + threadIdx.x) * 4;

    const float* src = nullptr; unsigned short* dst; long off, soff = 0;
    if (i4 < nXp) {
        dst = xb; off = i4;
        if      (off < oX)  { src = x;  soff = off; }
        else if (off < oS)  { src = s;  soff = off - oX; }
        else if (off < oTe) { src = te; soff = off - oS; }
    } else if (i4 < nXp + nW) {
        dst = wb; off = i4 - nXp; src = ipw; soff = off;
    } else if (i4 < nXp + nW + nOW) {
        dst = owb; off = i4 - nXp - nW; src = ow; soff = off;
    } else return;

    float4 v = make_float4(0.f, 0.f, 0.f, 0.f);
    if (src) v = *reinterpret_cast<const float4*>(src + soff);
    ushort4 o;
    o.x = f2bf(v.x); o.y = f2bf(v.y); o.z = f2bf(v.z); o.w = f2bf(v.w);
    *reinterpret_cast<ushort4*>(dst + off) = o;
}

struct DstPtrs { float* d[9]; };
struct BPtrs   { unsigned short* p[3]; };   // bf16 side-copies of q/k/v

__device__ __forceinline__ void load_lds16(const unsigned short* g, unsigned short* l) {
    __builtin_amdgcn_global_load_lds(
        (const __attribute__((address_space(1))) unsigned int*)g,
        (__attribute__((address_space(3))) unsigned int*)l,
        16, 0, 0);
}

// ---------------------------------------------------------------------------
// 256x256 bf16 GEMM, 16 waves (1024 thr), 4 waves/SIMD (R11 structure).
// R13: epilogue also emits bf16 side-copies of the main-segment outputs
// (q/k/v) so the attention kernel reads half the bytes and skips all f2bf.
// ---------------------------------------------------------------------------
__global__ __launch_bounds__(1024, 4) void mfma_gemm256(
    const unsigned short* __restrict__ A,
    const unsigned short* __restrict__ W,
    const float* __restrict__ bias,
    DstPtrs dp, BPtrs bp, int Mmain, int Ms, int Mte,
    int ntiles, int tilesPerSeg)
{
    __shared__ __align__(16) unsigned short Asm[2][256 * 64];  // 2 x 32 KB
    __shared__ __align__(16) unsigned short Bsm[2][256 * 64];  // 2 x 32 KB

    // bijective XCD swizzle (m204)
    const int nwg = gridDim.x;
    const int bid = blockIdx.x;
    const int q8 = nwg >> 3, r8 = nwg & 7;
    const int xcd = bid & 7, pos = bid >> 3;
    const int wgid = (xcd < r8 ? xcd * (q8 + 1)
                               : r8 * (q8 + 1) + (xcd - r8) * q8) + pos;
    const int mtile = wgid / ntiles;
    const int ntile = wgid - mtile * ntiles;

    const int tid  = threadIdx.x;
    const int wave = tid >> 6;         // 0..15
    const int lane = tid & 63;
    const int wm = wave >> 2;          // 0..3 (M quarter)
    const int wn = wave & 3;           // 0..3 (N quarter)
    const int m0  = mtile * 256;
    const int n0w = ntile * 256;
    const int seg = ntile / tilesPerSeg;
    const int n0g = (ntile % tilesPerSeg) * 256;

    const int frow = lane & 15;
    const int g    = lane >> 4;
    const int axr  = frow & 7;
    const int c0   = (g ^ axr) * 16;              // ks=0 chunk byte offset
    const int c1   = ((4 + g) ^ axr) * 16;        // ks=1

    f32x4 acc[4][4];
#pragma unroll
    for (int i = 0; i < 4; ++i)
#pragma unroll
        for (int j = 0; j < 4; ++j)
            acc[i][j] = f32x4{0.f, 0.f, 0.f, 0.f};

    const int srow = tid >> 3;                     // 0..127
    const int scol = ((tid & 7) ^ ((tid >> 3) & 7)) * 8;
    const int sdst = tid * 8;

    const unsigned short* gA = A + (size_t)(m0 + srow) * 768 + scol;
    const unsigned short* gB = W + (size_t)(n0w + srow) * 768 + scol;

    auto STAGE_A = [&](int kt, int b) {
        const int k1 = kt * 64;
#pragma unroll
        for (int r = 0; r < 2; ++r)
            load_lds16(gA + (size_t)(r * 128) * 768 + k1,
                       &Asm[b][(r * 128) * 64 + sdst]);
    };
    auto STAGE_B = [&](int kt, int b) {
        const int k1 = kt * 64;
#pragma unroll
        for (int r = 0; r < 2; ++r)
            load_lds16(gB + (size_t)(r * 128) * 768 + k1,
                       &Bsm[b][(r * 128) * 64 + sdst]);
    };

    STAGE_A(0, 0);
    STAGE_B(0, 0);
    asm volatile("s_waitcnt vmcnt(0)" ::: "memory");
    __builtin_amdgcn_s_barrier();
    __builtin_amdgcn_sched_barrier(0);

    const int arow0 = wm * 64 + frow;
    const int brow0 = wn * 64 + frow;

    for (int kt = 0; kt < 12; ++kt) {
        const int cur = kt & 1;
        const char* As_ = (const char*)&Asm[cur][0];
        const char* Bs_ = (const char*)&Bsm[cur][0];
        const bool pre = kt < 11;

        s16x8 afr[4], bfr[4];
        // ---- ks = 0 ----
#pragma unroll
        for (int m = 0; m < 4; ++m)
            afr[m] = *reinterpret_cast<const s16x8*>(As_ + (arow0 + m * 16) * 128 + c0);
#pragma unroll
        for (int n = 0; n < 4; ++n)
            bfr[n] = *reinterpret_cast<const s16x8*>(Bs_ + (brow0 + n * 16) * 128 + c0);
        if (pre) { STAGE_A(kt + 1, cur ^ 1); STAGE_B(kt + 1, cur ^ 1); }
        asm volatile("s_waitcnt lgkmcnt(0)" ::: "memory");
        __builtin_amdgcn_sched_barrier(0);
        __builtin_amdgcn_s_setprio(1);
#pragma unroll
        for (int m = 0; m < 4; ++m)
#pragma unroll
            for (int n = 0; n < 4; ++n)
                acc[m][n] = __builtin_amdgcn_mfma_f32_16x16x32_bf16(
                    afr[m], bfr[n], acc[m][n], 0, 0, 0);
        __builtin_amdgcn_s_setprio(0);
        // ---- ks = 1 ----
#pragma unroll
        for (int m = 0; m < 4; ++m)
            afr[m] = *reinterpret_cast<const s16x8*>(As_ + (arow0 + m * 16) * 128 + c1);
#pragma unroll
        for (int n = 0; n < 4; ++n)
            bfr[n] = *reinterpret_cast<const s16x8*>(Bs_ + (brow0 + n * 16) * 128 + c1);
        asm volatile("s_waitcnt lgkmcnt(0)" ::: "memory");
        __builtin_amdgcn_sched_barrier(0);
        __builtin_amdgcn_s_setprio(1);
#pragma unroll
        for (int m = 0; m < 4; ++m)
#pragma unroll
            for (int n = 0; n < 4; ++n)
                acc[m][n] = __builtin_amdgcn_mfma_f32_16x16x32_bf16(
                    afr[m], bfr[n], acc[m][n], 0, 0, 0);
        __builtin_amdgcn_s_setprio(0);
        __builtin_amdgcn_sched_barrier(0);
        asm volatile("s_waitcnt vmcnt(0)" ::: "memory");
        __builtin_amdgcn_s_barrier();
        __builtin_amdgcn_sched_barrier(0);
    }

    // ---- coalesced epilogue via per-wave LDS transpose (R10 pattern) ----
    {
        float* sc = (wave < 8 ? reinterpret_cast<float*>(&Asm[0][0])
                              : reinterpret_cast<float*>(&Bsm[0][0]))
                    + (wave & 7) * 1088;           // 16 x 68 f32 per wave
        float bv[4];
#pragma unroll
        for (int n = 0; n < 4; ++n)
            bv[n] = bias[n0w + wn * 64 + n * 16 + frow];

        const int erow = lane >> 2;       // 0..15
        const int ecg  = lane & 3;        // 0..3

#pragma unroll
        for (int m = 0; m < 4; ++m) {
#pragma unroll
            for (int n = 0; n < 4; ++n)
#pragma unroll
                for (int r = 0; r < 4; ++r)
                    sc[(g * 4 + r) * 68 + n * 16 + frow] = acc[m][n][r] + bv[n];

            const int grow = m0 + wm * 64 + m * 16 + erow;
            float* base = nullptr; int lr = 0; bool mainSeg = false;
            if (grow < Mmain)                 { base = dp.d[seg];     lr = grow; mainSeg = true; }
            else if (grow < Mmain + Ms)       { base = dp.d[3 + seg]; lr = grow - Mmain; }
            else if (grow < Mmain + Ms + Mte) { base = dp.d[6 + seg]; lr = grow - Mmain - Ms; }
            if (base) {
                float* p = base + (size_t)lr * 768 + n0g + wn * 64 + ecg * 16;
                const float* sr = sc + erow * 68 + ecg * 16;
                ushort4 ob[4];
#pragma unroll
                for (int kq = 0; kq < 4; ++kq) {
                    const float4 t = *reinterpret_cast<const float4*>(sr + kq * 4);
                    *reinterpret_cast<float4*>(p + kq * 4) = t;
                    ob[kq].x = f2bf(t.x); ob[kq].y = f2bf(t.y);
                    ob[kq].z = f2bf(t.z); ob[kq].w = f2bf(t.w);
                }
                if (mainSeg && bp.p[0]) {
                    unsigned short* pb = bp.p[seg] + (size_t)lr * 768
                                       + n0g + wn * 64 + ecg * 16;
#pragma unroll
                    for (int kq = 0; kq < 4; ++kq)
                        *reinterpret_cast<ushort4*>(pb + kq * 4) = ob[kq];
                }
            }
        }
    }
}

// ---------------------------------------------------------------------------
// 128x128 bf16 GEMM (R8 version) — kept for s_out only (M=128, 6 blocks).
// ---------------------------------------------------------------------------
__global__ __launch_bounds__(256) void mfma_gemm(
    const unsigned short* __restrict__ A,
    const unsigned short* __restrict__ W,
    const float* __restrict__ bias,
    DstPtrs dp, int Mmain, int Ms, int Mte,
    int ntiles, int tilesPerSeg)
{
    __shared__ __align__(16) unsigned short Asm[2][128 * 32];
    __shared__ __align__(16) unsigned short Bsm[2][128 * 32];

    const int nwg = gridDim.x;
    const int bid = blockIdx.x;
    const int q8 = nwg >> 3, r8 = nwg & 7;
    const int xcd = bid & 7, pos = bid >> 3;
    const int wgid = (xcd < r8 ? xcd * (q8 + 1)
                               : r8 * (q8 + 1) + (xcd - r8) * q8) + pos;
    const int mtile = wgid / ntiles;
    const int ntile = wgid - mtile * ntiles;

    const int tid  = threadIdx.x;
    const int wave = tid >> 6;
    const int lane = tid & 63;
    const int wr = wave >> 1, wc = wave & 1;
    const int m0  = mtile * 128;
    const int seg = ntile / tilesPerSeg;
    const int n0g = (ntile % tilesPerSeg) * 128;
    const int n0w = ntile * 128;

    f32x4 acc[4][4];
#pragma unroll
    for (int i = 0; i < 4; ++i)
#pragma unroll
        for (int j = 0; j < 4; ++j)
            acc[i][j] = f32x4{0.f, 0.f, 0.f, 0.f};

    const int srow = tid >> 2;
    const int scol = (((tid & 3) ^ ((tid >> 3) & 3))) * 8;
    const int woff = wave * 512;

    const int frow = lane & 15;
    const int fkc  = ((lane >> 4) ^ ((frow >> 1) & 3)) * 8;

    const unsigned short* gA = A + (size_t)(m0 + srow) * 768 + scol;
    const unsigned short* gB = W + (size_t)(n0w + srow) * 768 + scol;

#pragma unroll
    for (int it = 0; it < 2; ++it) {
        load_lds16(gA + (size_t)it * 64 * 768, &Asm[0][woff + it * 2048]);
        load_lds16(gB + (size_t)it * 64 * 768, &Bsm[0][woff + it * 2048]);
    }
    asm volatile("s_waitcnt vmcnt(0)" ::: "memory");
    __syncthreads();

    for (int t = 0; t < 24; ++t) {
        const int cur = t & 1;
        if (t < 23) {
            const int k1 = (t + 1) * 32;
#pragma unroll
            for (int it = 0; it < 2; ++it) {
                load_lds16(gA + k1 + (size_t)it * 64 * 768, &Asm[cur ^ 1][woff + it * 2048]);
                load_lds16(gB + k1 + (size_t)it * 64 * 768, &Bsm[cur ^ 1][woff + it * 2048]);
            }
        }

        s16x8 af[4], bf[4];
#pragma unroll
        for (int i = 0; i < 4; ++i) {
            const int ar = wr * 64 + i * 16 + frow;
            af[i] = *reinterpret_cast<const s16x8*>(&Asm[cur][ar * 32 + fkc]);
        }
#pragma unroll
        for (int j = 0; j < 4; ++j) {
            const int br = wc * 64 + j * 16 + frow;
            bf[j] = *reinterpret_cast<const s16x8*>(&Bsm[cur][br * 32 + fkc]);
        }
#pragma unroll
        for (int i = 0; i < 4; ++i)
#pragma unroll
            for (int j = 0; j < 4; ++j)
                acc[i][j] = __builtin_amdgcn_mfma_f32_16x16x32_bf16(
                    af[i], bf[j], acc[i][j], 0, 0, 0);

        asm volatile("s_waitcnt vmcnt(0)" ::: "memory");
        __syncthreads();
    }

#pragma unroll
    for (int j = 0; j < 4; ++j) {
        const int col = wc * 64 + j * 16 + (lane & 15);
        const float bv = bias[n0w + col];
#pragma unroll
        for (int i = 0; i < 4; ++i) {
            const int gmBase = m0 + wr * 64 + i * 16 + ((lane >> 4) << 2);
            float* base; int lr;
            if (gmBase < Mmain)                { base = dp.d[seg];     lr = gmBase; }
            else if (gmBase < Mmain + Ms)      { base = dp.d[3 + seg]; lr = gmBase - Mmain; }
            else if (gmBase < Mmain + Ms + Mte){ base = dp.d[6 + seg]; lr = gmBase - Mmain - Ms; }
            else continue;
            float* p = base + (size_t)lr * 768 + n0g + col;
#pragma unroll
            for (int r = 0; r < 4; ++r)
                p[(size_t)r * 768] = acc[i][j][r] + bv;
        }
    }
}

// ---------------------------------------------------------------------------
// MFMA self-attention + fused s-branch, P in registers (R12 structure).
// R13: q/k/v consumed from bf16 side-copies — staging is pure u16 repack
// (no f2bf), q-fragments are direct 16B loads, read traffic halves.
// ---------------------------------------------------------------------------
__global__ __launch_bounds__(512, 4) void attn_mfma(
    const unsigned short* __restrict__ qb, const unsigned short* __restrict__ kb,
    const unsigned short* __restrict__ vb, const float* __restrict__ sq,
    const float* __restrict__ tek, const float* __restrict__ tev,
    const float* __restrict__ pmask,
    unsigned short* __restrict__ mixb, float* __restrict__ smix)
{
    __shared__ __align__(16) unsigned short Ks[KkP * 64];      // 28 KB
    __shared__ __align__(16) unsigned short Vt[64 * 256];      // 32 KB
    __shared__ float pms[196];                                 // 0.8 KB

    const int bidx = blockIdx.x;
    const int h  = bidx % Hh;
    const int bt = bidx / Hh;
    const int b  = bt / Tt;
    const int tt = bt % Tt;
    const int tid  = threadIdx.x;
    const int wave = tid >> 6;          // 0..7
    const int lane = tid & 63;
    const int l15  = lane & 15;
    const int g    = lane >> 4;
    const size_t rbase = (size_t)bt * Ll * 768 + (size_t)h * Cc;

    // ---- stage K (bf16, swizzled 16B granules) ----
    for (int idx = tid; idx < KkP * 8; idx += 512) {
        const int row = idx >> 3;
        const int c8  = idx & 7;                 // 8-bf16 (16B) chunk
        s16x8 kv = s16x8{0,0,0,0,0,0,0,0};
        if (row < Ll)
            kv = *reinterpret_cast<const s16x8*>(kb + rbase + (size_t)row * 768 + c8 * 8);
        const int kbyte = (row * 128 + c8 * 16) ^ ((row & 7) << 4);
        *reinterpret_cast<s16x8*>((char*)Ks + kbyte) = kv;
    }
    // ---- stage V transposed (row-pair packed u32, pure repack) ----
    for (int idx = tid; idx < 112 * 8; idx += 512) {
        const int rp = idx >> 3;
        const int c8 = idx & 7;
        const int r0 = rp * 2, r1 = rp * 2 + 1;
        s16x8 a0 = s16x8{0,0,0,0,0,0,0,0};
        s16x8 a1 = s16x8{0,0,0,0,0,0,0,0};
        if (r0 < Ll) a0 = *reinterpret_cast<const s16x8*>(vb + rbase + (size_t)r0 * 768 + c8 * 8);
        if (r1 < Ll) a1 = *reinterpret_cast<const s16x8*>(vb + rbase + (size_t)r1 * 768 + c8 * 8);
#pragma unroll
        for (int i = 0; i < 8; ++i) {
            const int c = c8 * 8 + i;
            const unsigned int w = (unsigned)(unsigned short)a0[i]
                                 | ((unsigned)(unsigned short)a1[i] << 16);
            const int vbyte = (c * 512 + rp * 4) ^ ((c & 7) << 4);
            *reinterpret_cast<unsigned int*>((char*)Vt + vbyte) = w;
        }
    }
    for (int i = tid; i < 196; i += 512)
        pms[i] = pmask[(size_t)bt * 196 + i];
    __syncthreads();

    for (int qt = wave; qt < 14; qt += 8) {
        const bool stile = (qt == 13);
        s16x8 qf[2];
        float qte = 0.f;
        if (!stile) {
            const int qrow = qt * 16 + l15;
            if (qrow < Ll) {
                const unsigned short* qp = qb + rbase + (size_t)qrow * 768;
                qf[0] = *reinterpret_cast<const s16x8*>(qp + g * 8);
                qf[1] = *reinterpret_cast<const s16x8*>(qp + 32 + g * 8);
            } else {
                qf[0] = s16x8{0,0,0,0,0,0,0,0};
                qf[1] = s16x8{0,0,0,0,0,0,0,0};
            }
        } else {
            // s-branch: "Q" rows = sq[b, l15, h, :] (f32); qte = q . te_k
            const float* sp = sq + ((size_t)(b * QSs + l15)) * Ee + h * Cc;
            const float* tp = tek + (size_t)tt * Ee + h * Cc;
#pragma unroll
            for (int ks = 0; ks < 2; ++ks) {
                const float4 a = *reinterpret_cast<const float4*>(sp + ks * 32 + g * 8);
                const float4 c = *reinterpret_cast<const float4*>(sp + ks * 32 + g * 8 + 4);
                const float4 ta = *reinterpret_cast<const float4*>(tp + ks * 32 + g * 8);
                const float4 tc = *reinterpret_cast<const float4*>(tp + ks * 32 + g * 8 + 4);
                qf[ks] = s16x8{(short)f2bf(a.x), (short)f2bf(a.y), (short)f2bf(a.z), (short)f2bf(a.w),
                               (short)f2bf(c.x), (short)f2bf(c.y), (short)f2bf(c.z), (short)f2bf(c.w)};
                qte += a.x * ta.x + a.y * ta.y + a.z * ta.z + a.w * ta.w
                     + c.x * tc.x + c.y * tc.y + c.z * tc.z + c.w * tc.w;
            }
            qte += __shfl_xor(qte, 16);
            qte += __shfl_xor(qte, 32);
        }

        float lsq = 0.f;
        f32x4 oacc[4];
#pragma unroll
        for (int ct = 0; ct < 4; ++ct) oacc[ct] = f32x4{0.f, 0.f, 0.f, 0.f};

        for (int kt = 0; kt < 14; ++kt) {
            // QK^T slice: S^T[k=kt*16+g*4+r][q=l15]
            const int krow = kt * 16 + l15;
            f32x4 acc = {0.f, 0.f, 0.f, 0.f};
#pragma unroll
            for (int ks = 0; ks < 2; ++ks) {
                const int byte = (krow * 128 + ks * 64 + g * 16) ^ ((krow & 7) << 4);
                const s16x8 kf = *reinterpret_cast<const s16x8*>((const char*)Ks + byte);
                acc = __builtin_amdgcn_mfma_f32_16x16x32_bf16(kf, qf[ks], acc, 0, 0, 0);
            }
            float p[4];
#pragma unroll
            for (int r = 0; r < 4; ++r) {
                const int kg = kt * 16 + g * 4 + r;
                float pv;
                if (!stile)
                    pv = (kg < Ll) ? __expf(acc[r] * 0.125f) : 0.f;
                else
                    pv = (kg >= 1 && kg < Ll)
                         ? __expf((acc[r] + qte) * 0.125f + pms[kg - 1]) : 0.f;
                p[r] = pv;
                lsq += pv;
            }
            // PV per-kt, K=16: A-frag = p (already in the right layout)
            const s16x4 pa = s16x4{(short)f2bf(p[0]), (short)f2bf(p[1]),
                                   (short)f2bf(p[2]), (short)f2bf(p[3])};
            const int kb2 = (kt * 16 + g * 4) * 2;   // byte offset within a Vt row
#pragma unroll
            for (int ct = 0; ct < 4; ++ct) {
                const int crow = ct * 16 + l15;
                const int vbyte = (crow * 512 + kb2) ^ ((crow & 7) << 4);
                const s16x4 vbf = *reinterpret_cast<const s16x4*>((const char*)Vt + vbyte);
                oacc[ct] = __builtin_amdgcn_mfma_f32_16x16x16bf16_1k(
                    pa, vbf, oacc[ct], 0, 0, 0);
            }
        }
        lsq += __shfl_xor(lsq, 16);
        lsq += __shfl_xor(lsq, 32);
        const float invl = 1.f / lsq;

#pragma unroll
        for (int ct = 0; ct < 4; ++ct) {
#pragma unroll
            for (int r = 0; r < 4; ++r) {
                const int qw = g * 4 + r;
                const float iv = __shfl(invl, qw);
                if (!stile) {
                    const int qg = qt * 16 + qw;
                    if (qg < Ll)
                        mixb[(size_t)(bt * Ll + qg) * Ee + h * Cc + ct * 16 + l15] =
                            f2bf(oacc[ct][r] * iv);
                } else {
                    const int c = ct * 16 + l15;
                    const float tv = tev[(size_t)tt * Ee + h * Cc + c];
                    smix[((size_t)(bt * QSs + qw)) * Ee + h * Cc + c] =
                        oacc[ct][r] * iv + tv;
                }
            }
        }
    }
}

// ---------------------------------------------------------------------------
// Depthwise conv over T + residual + bias, mean over T -> bf16.
// ---------------------------------------------------------------------------
__global__ __launch_bounds__(256) void conv_mean_kernel(
    const float* __restrict__ smix, const float* __restrict__ cw,
    const float* __restrict__ cb, unsigned short* __restrict__ meansm_b)
{
    const int idx = blockIdx.x * 256 + threadIdx.x;
    if (idx >= Bb * QSs * Ee) return;
    const int e  = idx % Ee;
    const int n  = idx / Ee;
    const int b  = n / QSs;
    const int qi = n % QSs;

    float v0 = 0.f, vlast = 0.f, S = 0.f;
#pragma unroll
    for (int t = 0; t < Tt; ++t) {
        const float val = smix[((size_t)(b * Tt + t) * QSs + qi) * Ee + e];
        if (t == 0) v0 = val;
        if (t == Tt - 1) vlast = val;
        S += val;
    }
    const float w0 = cw[e * 3 + 0], w1 = cw[e * 3 + 1], w2 = cw[e * 3 + 2];
    const float tot = S + w0 * (S - vlast) + w1 * S + w2 * (S - v0);
    meansm_b[idx] = f2bf(tot * (1.f / Tt) + cb[e]);
}

// ---------------------------------------------------------------------------
extern "C" void kernel_launch(void* const* d_in, const int* in_sizes, int n_in,
                              void* d_out, int out_size, void* d_ws, size_t ws_size,
                              hipStream_t stream)
{
    const float* x     = (const float*)d_in[0];
    const float* s     = (const float*)d_in[1];
    const float* te    = (const float*)d_in[2];
    const float* pmask = (const float*)d_in[3];
    const float* ipw   = (const float*)d_in[4];
    const float* ipb   = (const float*)d_in[5];
    const float* ow    = (const float*)d_in[6];
    const float* ob    = (const float*)d_in[7];
    const float* cw    = (const float*)d_in[8];
    const float* cb    = (const float*)d_in[9];

    float* out = (float*)d_out;
    const size_t NX = (size_t)MX;
    float* q_o    = out;
    float* k_o    = q_o  + NX * Ee;
    float* v_o    = k_o  + NX * Ee;
    float* out_o  = v_o  + NX * Ee;
    float* sq_o   = out_o + NX * Ee;
    float* sk_o   = sq_o + (size_t)MS * Ee;
    float* sv_o   = sk_o + (size_t)MS * Ee;
    float* sout_o = sv_o + (size_t)MS * Ee;

    char* wsb = (char*)d_ws;
    unsigned short* xb   = (unsigned short*)wsb;                  // 12800*768 bf16 (reused as mixb)
    unsigned short* wb   = xb + (size_t)MPAD * Ee;                // 2304*768
    unsigned short* owb  = wb + (size_t)3 * Ee * Ee;              // 768*768
    unsigned short* meansm_b = owb + (size_t)Ee * Ee;             // 128*768 bf16
    float* teq    = (float*)(meansm_b + (size_t)MS * Ee);
    float* tek    = teq + (size_t)MTE * Ee;
    float* tev    = tek + (size_t)MTE * Ee;
    float* smix   = tev + (size_t)MTE * Ee;                       // 64*16*768 f32
    unsigned short* qb = (unsigned short*)(smix + (size_t)Bb * Tt * QSs * Ee);
    unsigned short* kbq = qb + (size_t)MX * Ee;                   // 12608*768 bf16 each
    unsigned short* vbq = kbq + (size_t)MX * Ee;
    unsigned short* mixb = xb;

    const long nXp = (long)MPAD * Ee;
    const long nW  = (long)3 * Ee * Ee;
    const long nOW = (long)Ee * Ee;
    const long nCvt = (nXp + nW + nOW) / 4;

    // 1. fused converts
    convert_all<<<dim3((nCvt + 255) / 256), 256, 0, stream>>>(
        x, s, te, ipw, ow, xb, wb, owb);

    // 2. Fused QKV projection (256-tile 16-wave) + bf16 side-copies of q/k/v
    {
        DstPtrs dp;
        dp.d[0] = q_o;  dp.d[1] = k_o;  dp.d[2] = v_o;
        dp.d[3] = sq_o; dp.d[4] = sk_o; dp.d[5] = sv_o;
        dp.d[6] = teq;  dp.d[7] = tek;  dp.d[8] = tev;
        BPtrs bp; bp.p[0] = qb; bp.p[1] = kbq; bp.p[2] = vbq;
        mfma_gemm256<<<dim3((MPAD / 256) * 9), 1024, 0, stream>>>(
            xb, wb, ipb, dp, bp, MX, MS, MTE, 9, 3);
    }

    // 3. self-attention (bf16 inputs, P-in-registers) + fused s-branch
    attn_mfma<<<dim3(Bb * Tt * Hh), 512, 0, stream>>>(
        qb, kbq, vbq, sq_o, tek, tev, pmask, mixb, smix);

    // 4. output projection (256-tile 16-wave, grid 50*3 = 150)
    {
        DstPtrs dp;
        for (int i = 0; i < 9; ++i) dp.d[i] = out_o;
        BPtrs bp; bp.p[0] = nullptr; bp.p[1] = nullptr; bp.p[2] = nullptr;
        mfma_gemm256<<<dim3((MPAD / 256) * 3), 1024, 0, stream>>>(
            mixb, owb, ob, dp, bp, MX, 0, 0, 3, 3);
    }

    // 5. conv + residual + mean over T -> bf16
    conv_mean_kernel<<<dim3((Bb * QSs * Ee + 255) / 256), 256, 0, stream>>>(
        smix, cw, cb, meansm_b);

    // 6. s_out projection (128-tile kernel, M=128, grid 6)
    {
        DstPtrs dp;
        for (int i = 0; i < 9; ++i) dp.d[i] = sout_o;
        mfma_gemm<<<dim3(6), 256, 0, stream>>>(
            meansm_b, owb, ob, dp, MS, 0, 0, 6, 6);
    }
}

// Round 14
// 203.171 us; speedup vs baseline: 1.0346x; 1.0346x over previous
//
#include <hip/hip_runtime.h>
#include <math.h>

// Problem constants
constexpr int Bb  = 8;
constexpr int Tt  = 8;
constexpr int Ll  = 197;
constexpr int Ee  = 768;
constexpr int Hh  = 12;
constexpr int QSs = 16;
constexpr int Cc  = 64;   // Ee / Hh
constexpr int MX    = Bb * Tt * Ll;        // 12608 rows of x
constexpr int MS    = Bb * QSs;            // 128 rows of s
constexpr int MTE   = Tt;                  // 8 rows of te
constexpr int MPAD  = 12800;               // 50 * 256
constexpr int KkP = 224;                   // 14*16 k-pad for attn

using f32x4 = __attribute__((ext_vector_type(4))) float;
using s16x8 = __attribute__((ext_vector_type(8))) short;
using s16x4 = __attribute__((ext_vector_type(4))) short;

__device__ __forceinline__ unsigned short f2bf(float f) {
    unsigned int u = __float_as_uint(f);
    u = (u + 0x7fffu + ((u >> 16) & 1u)) >> 16;
    return (unsigned short)u;
}

// ---------------------------------------------------------------------------
// Fused f32 -> bf16 converts: [x | s | te | zeros] into xb (MPAD rows),
// plus in_proj_weight and out_w. One launch.
// ---------------------------------------------------------------------------
__global__ __launch_bounds__(256) void convert_all(
    const float* __restrict__ x, const float* __restrict__ s,
    const float* __restrict__ te, const float* __restrict__ ipw,
    const float* __restrict__ ow, unsigned short* __restrict__ xb,
    unsigned short* __restrict__ wb, unsigned short* __restrict__ owb)
{
    const long oX  = (long)MX * Ee;
    const long oS  = oX + (long)MS * Ee;
    const long oTe = oS + (long)MTE * Ee;
    const long nXp = (long)MPAD * Ee;
    const long nW  = (long)3 * Ee * Ee;
    const long nOW = (long)Ee * Ee;
    const long i4 = ((long)blockIdx.x * 256 + threadIdx.x) * 4;

    const float* src = nullptr; unsigned short* dst; long off, soff = 0;
    if (i4 < nXp) {
        dst = xb; off = i4;
        if      (off < oX)  { src = x;  soff = off; }
        else if (off < oS)  { src = s;  soff = off - oX; }
        else if (off < oTe) { src = te; soff = off - oS; }
    } else if (i4 < nXp + nW) {
        dst = wb; off = i4 - nXp; src = ipw; soff = off;
    } else if (i4 < nXp + nW + nOW) {
        dst = owb; off = i4 - nXp - nW; src = ow; soff = off;
    } else return;

    float4 v = make_float4(0.f, 0.f, 0.f, 0.f);
    if (src) v = *reinterpret_cast<const float4*>(src + soff);
    ushort4 o;
    o.x = f2bf(v.x); o.y = f2bf(v.y); o.z = f2bf(v.z); o.w = f2bf(v.w);
    *reinterpret_cast<ushort4*>(dst + off) = o;
}

struct DstPtrs { float* d[9]; };

__device__ __forceinline__ void load_lds16(const unsigned short* g, unsigned short* l) {
    __builtin_amdgcn_global_load_lds(
        (const __attribute__((address_space(1))) unsigned int*)g,
        (__attribute__((address_space(3))) unsigned int*)l,
        16, 0, 0);
}

// ---------------------------------------------------------------------------
// 256x256 bf16 GEMM, 16 waves (1024 thr), 4 waves/SIMD. (R11/R12 structure,
// R14: reverted to pure-f32 epilogue — R13's bf16 side-copy cost the QKV
// dispatch +58MB writes / +25us, more than attn saved.)
// ---------------------------------------------------------------------------
__global__ __launch_bounds__(1024, 4) void mfma_gemm256(
    const unsigned short* __restrict__ A,
    const unsigned short* __restrict__ W,
    const float* __restrict__ bias,
    DstPtrs dp, int Mmain, int Ms, int Mte,
    int ntiles, int tilesPerSeg)
{
    __shared__ __align__(16) unsigned short Asm[2][256 * 64];  // 2 x 32 KB
    __shared__ __align__(16) unsigned short Bsm[2][256 * 64];  // 2 x 32 KB

    // bijective XCD swizzle (m204)
    const int nwg = gridDim.x;
    const int bid = blockIdx.x;
    const int q8 = nwg >> 3, r8 = nwg & 7;
    const int xcd = bid & 7, pos = bid >> 3;
    const int wgid = (xcd < r8 ? xcd * (q8 + 1)
                               : r8 * (q8 + 1) + (xcd - r8) * q8) + pos;
    const int mtile = wgid / ntiles;
    const int ntile = wgid - mtile * ntiles;

    const int tid  = threadIdx.x;
    const int wave = tid >> 6;         // 0..15
    const int lane = tid & 63;
    const int wm = wave >> 2;          // 0..3 (M quarter)
    const int wn = wave & 3;           // 0..3 (N quarter)
    const int m0  = mtile * 256;
    const int n0w = ntile * 256;
    const int seg = ntile / tilesPerSeg;
    const int n0g = (ntile % tilesPerSeg) * 256;

    const int frow = lane & 15;
    const int g    = lane >> 4;
    const int axr  = frow & 7;
    const int c0   = (g ^ axr) * 16;              // ks=0 chunk byte offset
    const int c1   = ((4 + g) ^ axr) * 16;        // ks=1

    f32x4 acc[4][4];
#pragma unroll
    for (int i = 0; i < 4; ++i)
#pragma unroll
        for (int j = 0; j < 4; ++j)
            acc[i][j] = f32x4{0.f, 0.f, 0.f, 0.f};

    const int srow = tid >> 3;                     // 0..127
    const int scol = ((tid & 7) ^ ((tid >> 3) & 7)) * 8;
    const int sdst = tid * 8;

    const unsigned short* gA = A + (size_t)(m0 + srow) * 768 + scol;
    const unsigned short* gB = W + (size_t)(n0w + srow) * 768 + scol;

    auto STAGE_A = [&](int kt, int b) {
        const int k1 = kt * 64;
#pragma unroll
        for (int r = 0; r < 2; ++r)
            load_lds16(gA + (size_t)(r * 128) * 768 + k1,
                       &Asm[b][(r * 128) * 64 + sdst]);
    };
    auto STAGE_B = [&](int kt, int b) {
        const int k1 = kt * 64;
#pragma unroll
        for (int r = 0; r < 2; ++r)
            load_lds16(gB + (size_t)(r * 128) * 768 + k1,
                       &Bsm[b][(r * 128) * 64 + sdst]);
    };

    STAGE_A(0, 0);
    STAGE_B(0, 0);
    asm volatile("s_waitcnt vmcnt(0)" ::: "memory");
    __builtin_amdgcn_s_barrier();
    __builtin_amdgcn_sched_barrier(0);

    const int arow0 = wm * 64 + frow;
    const int brow0 = wn * 64 + frow;

    for (int kt = 0; kt < 12; ++kt) {
        const int cur = kt & 1;
        const char* As_ = (const char*)&Asm[cur][0];
        const char* Bs_ = (const char*)&Bsm[cur][0];
        const bool pre = kt < 11;

        s16x8 afr[4], bfr[4];
        // ---- ks = 0 ----
#pragma unroll
        for (int m = 0; m < 4; ++m)
            afr[m] = *reinterpret_cast<const s16x8*>(As_ + (arow0 + m * 16) * 128 + c0);
#pragma unroll
        for (int n = 0; n < 4; ++n)
            bfr[n] = *reinterpret_cast<const s16x8*>(Bs_ + (brow0 + n * 16) * 128 + c0);
        if (pre) { STAGE_A(kt + 1, cur ^ 1); STAGE_B(kt + 1, cur ^ 1); }
        asm volatile("s_waitcnt lgkmcnt(0)" ::: "memory");
        __builtin_amdgcn_sched_barrier(0);
        __builtin_amdgcn_s_setprio(1);
#pragma unroll
        for (int m = 0; m < 4; ++m)
#pragma unroll
            for (int n = 0; n < 4; ++n)
                acc[m][n] = __builtin_amdgcn_mfma_f32_16x16x32_bf16(
                    afr[m], bfr[n], acc[m][n], 0, 0, 0);
        __builtin_amdgcn_s_setprio(0);
        // ---- ks = 1 ----
#pragma unroll
        for (int m = 0; m < 4; ++m)
            afr[m] = *reinterpret_cast<const s16x8*>(As_ + (arow0 + m * 16) * 128 + c1);
#pragma unroll
        for (int n = 0; n < 4; ++n)
            bfr[n] = *reinterpret_cast<const s16x8*>(Bs_ + (brow0 + n * 16) * 128 + c1);
        asm volatile("s_waitcnt lgkmcnt(0)" ::: "memory");
        __builtin_amdgcn_sched_barrier(0);
        __builtin_amdgcn_s_setprio(1);
#pragma unroll
        for (int m = 0; m < 4; ++m)
#pragma unroll
            for (int n = 0; n < 4; ++n)
                acc[m][n] = __builtin_amdgcn_mfma_f32_16x16x32_bf16(
                    afr[m], bfr[n], acc[m][n], 0, 0, 0);
        __builtin_amdgcn_s_setprio(0);
        __builtin_amdgcn_sched_barrier(0);
        asm volatile("s_waitcnt vmcnt(0)" ::: "memory");
        __builtin_amdgcn_s_barrier();
        __builtin_amdgcn_sched_barrier(0);
    }

    // ---- coalesced epilogue via per-wave LDS transpose (R10 pattern) ----
    {
        float* sc = (wave < 8 ? reinterpret_cast<float*>(&Asm[0][0])
                              : reinterpret_cast<float*>(&Bsm[0][0]))
                    + (wave & 7) * 1088;           // 16 x 68 f32 per wave
        float bv[4];
#pragma unroll
        for (int n = 0; n < 4; ++n)
            bv[n] = bias[n0w + wn * 64 + n * 16 + frow];

        const int erow = lane >> 2;       // 0..15
        const int ecg  = lane & 3;        // 0..3

#pragma unroll
        for (int m = 0; m < 4; ++m) {
#pragma unroll
            for (int n = 0; n < 4; ++n)
#pragma unroll
                for (int r = 0; r < 4; ++r)
                    sc[(g * 4 + r) * 68 + n * 16 + frow] = acc[m][n][r] + bv[n];

            const int grow = m0 + wm * 64 + m * 16 + erow;
            float* base = nullptr; int lr = 0;
            if (grow < Mmain)                 { base = dp.d[seg];     lr = grow; }
            else if (grow < Mmain + Ms)       { base = dp.d[3 + seg]; lr = grow - Mmain; }
            else if (grow < Mmain + Ms + Mte) { base = dp.d[6 + seg]; lr = grow - Mmain - Ms; }
            if (base) {
                float* p = base + (size_t)lr * 768 + n0g + wn * 64 + ecg * 16;
                const float* sr = sc + erow * 68 + ecg * 16;
#pragma unroll
                for (int kq = 0; kq < 4; ++kq)
                    *reinterpret_cast<float4*>(p + kq * 4) =
                        *reinterpret_cast<const float4*>(sr + kq * 4);
            }
        }
    }
}

// ---------------------------------------------------------------------------
// 128x128 bf16 GEMM (R8 version) — kept for s_out only (M=128, 6 blocks).
// ---------------------------------------------------------------------------
__global__ __launch_bounds__(256) void mfma_gemm(
    const unsigned short* __restrict__ A,
    const unsigned short* __restrict__ W,
    const float* __restrict__ bias,
    DstPtrs dp, int Mmain, int Ms, int Mte,
    int ntiles, int tilesPerSeg)
{
    __shared__ __align__(16) unsigned short Asm[2][128 * 32];
    __shared__ __align__(16) unsigned short Bsm[2][128 * 32];

    const int nwg = gridDim.x;
    const int bid = blockIdx.x;
    const int q8 = nwg >> 3, r8 = nwg & 7;
    const int xcd = bid & 7, pos = bid >> 3;
    const int wgid = (xcd < r8 ? xcd * (q8 + 1)
                               : r8 * (q8 + 1) + (xcd - r8) * q8) + pos;
    const int mtile = wgid / ntiles;
    const int ntile = wgid - mtile * ntiles;

    const int tid  = threadIdx.x;
    const int wave = tid >> 6;
    const int lane = tid & 63;
    const int wr = wave >> 1, wc = wave & 1;
    const int m0  = mtile * 128;
    const int seg = ntile / tilesPerSeg;
    const int n0g = (ntile % tilesPerSeg) * 128;
    const int n0w = ntile * 128;

    f32x4 acc[4][4];
#pragma unroll
    for (int i = 0; i < 4; ++i)
#pragma unroll
        for (int j = 0; j < 4; ++j)
            acc[i][j] = f32x4{0.f, 0.f, 0.f, 0.f};

    const int srow = tid >> 2;
    const int scol = (((tid & 3) ^ ((tid >> 3) & 3))) * 8;
    const int woff = wave * 512;

    const int frow = lane & 15;
    const int fkc  = ((lane >> 4) ^ ((frow >> 1) & 3)) * 8;

    const unsigned short* gA = A + (size_t)(m0 + srow) * 768 + scol;
    const unsigned short* gB = W + (size_t)(n0w + srow) * 768 + scol;

#pragma unroll
    for (int it = 0; it < 2; ++it) {
        load_lds16(gA + (size_t)it * 64 * 768, &Asm[0][woff + it * 2048]);
        load_lds16(gB + (size_t)it * 64 * 768, &Bsm[0][woff + it * 2048]);
    }
    asm volatile("s_waitcnt vmcnt(0)" ::: "memory");
    __syncthreads();

    for (int t = 0; t < 24; ++t) {
        const int cur = t & 1;
        if (t < 23) {
            const int k1 = (t + 1) * 32;
#pragma unroll
            for (int it = 0; it < 2; ++it) {
                load_lds16(gA + k1 + (size_t)it * 64 * 768, &Asm[cur ^ 1][woff + it * 2048]);
                load_lds16(gB + k1 + (size_t)it * 64 * 768, &Bsm[cur ^ 1][woff + it * 2048]);
            }
        }

        s16x8 af[4], bf[4];
#pragma unroll
        for (int i = 0; i < 4; ++i) {
            const int ar = wr * 64 + i * 16 + frow;
            af[i] = *reinterpret_cast<const s16x8*>(&Asm[cur][ar * 32 + fkc]);
        }
#pragma unroll
        for (int j = 0; j < 4; ++j) {
            const int br = wc * 64 + j * 16 + frow;
            bf[j] = *reinterpret_cast<const s16x8*>(&Bsm[cur][br * 32 + fkc]);
        }
#pragma unroll
        for (int i = 0; i < 4; ++i)
#pragma unroll
            for (int j = 0; j < 4; ++j)
                acc[i][j] = __builtin_amdgcn_mfma_f32_16x16x32_bf16(
                    af[i], bf[j], acc[i][j], 0, 0, 0);

        asm volatile("s_waitcnt vmcnt(0)" ::: "memory");
        __syncthreads();
    }

#pragma unroll
    for (int j = 0; j < 4; ++j) {
        const int col = wc * 64 + j * 16 + (lane & 15);
        const float bv = bias[n0w + col];
#pragma unroll
        for (int i = 0; i < 4; ++i) {
            const int gmBase = m0 + wr * 64 + i * 16 + ((lane >> 4) << 2);
            float* base; int lr;
            if (gmBase < Mmain)                { base = dp.d[seg];     lr = gmBase; }
            else if (gmBase < Mmain + Ms)      { base = dp.d[3 + seg]; lr = gmBase - Mmain; }
            else if (gmBase < Mmain + Ms + Mte){ base = dp.d[6 + seg]; lr = gmBase - Mmain - Ms; }
            else continue;
            float* p = base + (size_t)lr * 768 + n0g + col;
#pragma unroll
            for (int r = 0; r < 4; ++r)
                p[(size_t)r * 768] = acc[i][j][r] + bv;
        }
    }
}

// ---------------------------------------------------------------------------
// MFMA self-attention + fused s-branch, P in registers (R12 structure,
// restored verbatim: q/k/v read as f32, converted during staging).
// ---------------------------------------------------------------------------
__global__ __launch_bounds__(512, 4) void attn_mfma(
    const float* __restrict__ q, const float* __restrict__ k,
    const float* __restrict__ v, const float* __restrict__ sq,
    const float* __restrict__ tek, const float* __restrict__ tev,
    const float* __restrict__ pmask,
    unsigned short* __restrict__ mixb, float* __restrict__ smix)
{
    __shared__ __align__(16) unsigned short Ks[KkP * 64];      // 28 KB
    __shared__ __align__(16) unsigned short Vt[64 * 256];      // 32 KB
    __shared__ float pms[196];                                 // 0.8 KB

    const int bidx = blockIdx.x;
    const int h  = bidx % Hh;
    const int bt = bidx / Hh;
    const int b  = bt / Tt;
    const int tt = bt % Tt;
    const int tid  = threadIdx.x;
    const int wave = tid >> 6;          // 0..7
    const int lane = tid & 63;
    const int l15  = lane & 15;
    const int g    = lane >> 4;
    const size_t gbase = (size_t)bt * Ll * Ee + (size_t)h * Cc;

    // ---- stage K (row-major bf16, swizzled) ----
    for (int idx = tid; idx < KkP * 16; idx += 512) {
        const int row = idx >> 4;
        const int cg  = idx & 15;
        float4 kv = make_float4(0.f, 0.f, 0.f, 0.f);
        if (row < Ll)
            kv = *reinterpret_cast<const float4*>(k + gbase + (size_t)row * Ee + cg * 4);
        ushort4 kb; kb.x = f2bf(kv.x); kb.y = f2bf(kv.y); kb.z = f2bf(kv.z); kb.w = f2bf(kv.w);
        const int kbyte = (row * 128 + cg * 8) ^ ((row & 7) << 4);
        *reinterpret_cast<ushort4*>((char*)Ks + kbyte) = kb;
    }
    // ---- stage V transposed (row-pair packed u32) ----
    for (int idx = tid; idx < 112 * 16; idx += 512) {
        const int rp = idx >> 4;
        const int cg = idx & 15;
        const int r0 = rp * 2, r1 = rp * 2 + 1;
        float4 v0 = make_float4(0.f, 0.f, 0.f, 0.f);
        float4 v1 = make_float4(0.f, 0.f, 0.f, 0.f);
        if (r0 < Ll) v0 = *reinterpret_cast<const float4*>(v + gbase + (size_t)r0 * Ee + cg * 4);
        if (r1 < Ll) v1 = *reinterpret_cast<const float4*>(v + gbase + (size_t)r1 * Ee + cg * 4);
        const float a0[4] = {v0.x, v0.y, v0.z, v0.w};
        const float a1[4] = {v1.x, v1.y, v1.z, v1.w};
#pragma unroll
        for (int i = 0; i < 4; ++i) {
            const int c = cg * 4 + i;
            const unsigned int w = (unsigned)f2bf(a0[i]) | ((unsigned)f2bf(a1[i]) << 16);
            const int vbyte = (c * 512 + rp * 4) ^ ((c & 7) << 4);
            *reinterpret_cast<unsigned int*>((char*)Vt + vbyte) = w;
        }
    }
    for (int i = tid; i < 196; i += 512)
        pms[i] = pmask[(size_t)bt * 196 + i];
    __syncthreads();

    for (int qt = wave; qt < 14; qt += 8) {
        const bool stile = (qt == 13);
        s16x8 qf[2];
        float qte = 0.f;
        if (!stile) {
            const int qrow = qt * 16 + l15;
            const float* qp = q + gbase + (size_t)qrow * Ee;
#pragma unroll
            for (int ks = 0; ks < 2; ++ks) {
                float4 a = make_float4(0.f, 0.f, 0.f, 0.f);
                float4 c = make_float4(0.f, 0.f, 0.f, 0.f);
                if (qrow < Ll) {
                    a = *reinterpret_cast<const float4*>(qp + ks * 32 + g * 8);
                    c = *reinterpret_cast<const float4*>(qp + ks * 32 + g * 8 + 4);
                }
                qf[ks] = s16x8{(short)f2bf(a.x), (short)f2bf(a.y), (short)f2bf(a.z), (short)f2bf(a.w),
                               (short)f2bf(c.x), (short)f2bf(c.y), (short)f2bf(c.z), (short)f2bf(c.w)};
            }
        } else {
            // s-branch: "Q" rows = sq[b, l15, h, :]; qte = q . te_k (f32)
            const float* sp = sq + ((size_t)(b * QSs + l15)) * Ee + h * Cc;
            const float* tp = tek + (size_t)tt * Ee + h * Cc;
#pragma unroll
            for (int ks = 0; ks < 2; ++ks) {
                const float4 a = *reinterpret_cast<const float4*>(sp + ks * 32 + g * 8);
                const float4 c = *reinterpret_cast<const float4*>(sp + ks * 32 + g * 8 + 4);
                const float4 ta = *reinterpret_cast<const float4*>(tp + ks * 32 + g * 8);
                const float4 tc = *reinterpret_cast<const float4*>(tp + ks * 32 + g * 8 + 4);
                qf[ks] = s16x8{(short)f2bf(a.x), (short)f2bf(a.y), (short)f2bf(a.z), (short)f2bf(a.w),
                               (short)f2bf(c.x), (short)f2bf(c.y), (short)f2bf(c.z), (short)f2bf(c.w)};
                qte += a.x * ta.x + a.y * ta.y + a.z * ta.z + a.w * ta.w
                     + c.x * tc.x + c.y * tc.y + c.z * tc.z + c.w * tc.w;
            }
            qte += __shfl_xor(qte, 16);
            qte += __shfl_xor(qte, 32);
        }

        float lsq = 0.f;
        f32x4 oacc[4];
#pragma unroll
        for (int ct = 0; ct < 4; ++ct) oacc[ct] = f32x4{0.f, 0.f, 0.f, 0.f};

        for (int kt = 0; kt < 14; ++kt) {
            // QK^T slice: S^T[k=kt*16+g*4+r][q=l15]
            const int krow = kt * 16 + l15;
            f32x4 acc = {0.f, 0.f, 0.f, 0.f};
#pragma unroll
            for (int ks = 0; ks < 2; ++ks) {
                const int byte = (krow * 128 + ks * 64 + g * 16) ^ ((krow & 7) << 4);
                const s16x8 kf = *reinterpret_cast<const s16x8*>((const char*)Ks + byte);
                acc = __builtin_amdgcn_mfma_f32_16x16x32_bf16(kf, qf[ks], acc, 0, 0, 0);
            }
            float p[4];
#pragma unroll
            for (int r = 0; r < 4; ++r) {
                const int kg = kt * 16 + g * 4 + r;
                float pv;
                if (!stile)
                    pv = (kg < Ll) ? __expf(acc[r] * 0.125f) : 0.f;
                else
                    pv = (kg >= 1 && kg < Ll)
                         ? __expf((acc[r] + qte) * 0.125f + pms[kg - 1]) : 0.f;
                p[r] = pv;
                lsq += pv;
            }
            // PV per-kt, K=16: A-frag = p (already in the right layout)
            const s16x4 pa = s16x4{(short)f2bf(p[0]), (short)f2bf(p[1]),
                                   (short)f2bf(p[2]), (short)f2bf(p[3])};
            const int kb = (kt * 16 + g * 4) * 2;   // byte offset within a Vt row
#pragma unroll
            for (int ct = 0; ct < 4; ++ct) {
                const int crow = ct * 16 + l15;
                const int vbyte = (crow * 512 + kb) ^ ((crow & 7) << 4);
                const s16x4 vb = *reinterpret_cast<const s16x4*>((const char*)Vt + vbyte);
                oacc[ct] = __builtin_amdgcn_mfma_f32_16x16x16bf16_1k(
                    pa, vb, oacc[ct], 0, 0, 0);
            }
        }
        lsq += __shfl_xor(lsq, 16);
        lsq += __shfl_xor(lsq, 32);
        const float invl = 1.f / lsq;

#pragma unroll
        for (int ct = 0; ct < 4; ++ct) {
#pragma unroll
            for (int r = 0; r < 4; ++r) {
                const int qw = g * 4 + r;
                const float iv = __shfl(invl, qw);
                if (!stile) {
                    const int qg = qt * 16 + qw;
                    if (qg < Ll)
                        mixb[(size_t)(bt * Ll + qg) * Ee + h * Cc + ct * 16 + l15] =
                            f2bf(oacc[ct][r] * iv);
                } else {
                    const int c = ct * 16 + l15;
                    const float tv = tev[(size_t)tt * Ee + h * Cc + c];
                    smix[((size_t)(bt * QSs + qw)) * Ee + h * Cc + c] =
                        oacc[ct][r] * iv + tv;
                }
            }
        }
    }
}

// ---------------------------------------------------------------------------
// Depthwise conv over T + residual + bias, mean over T -> bf16.
// ---------------------------------------------------------------------------
__global__ __launch_bounds__(256) void conv_mean_kernel(
    const float* __restrict__ smix, const float* __restrict__ cw,
    const float* __restrict__ cb, unsigned short* __restrict__ meansm_b)
{
    const int idx = blockIdx.x * 256 + threadIdx.x;
    if (idx >= Bb * QSs * Ee) return;
    const int e  = idx % Ee;
    const int n  = idx / Ee;
    const int b  = n / QSs;
    const int qi = n % QSs;

    float v0 = 0.f, vlast = 0.f, S = 0.f;
#pragma unroll
    for (int t = 0; t < Tt; ++t) {
        const float val = smix[((size_t)(b * Tt + t) * QSs + qi) * Ee + e];
        if (t == 0) v0 = val;
        if (t == Tt - 1) vlast = val;
        S += val;
    }
    const float w0 = cw[e * 3 + 0], w1 = cw[e * 3 + 1], w2 = cw[e * 3 + 2];
    const float tot = S + w0 * (S - vlast) + w1 * S + w2 * (S - v0);
    meansm_b[idx] = f2bf(tot * (1.f / Tt) + cb[e]);
}

// ---------------------------------------------------------------------------
extern "C" void kernel_launch(void* const* d_in, const int* in_sizes, int n_in,
                              void* d_out, int out_size, void* d_ws, size_t ws_size,
                              hipStream_t stream)
{
    const float* x     = (const float*)d_in[0];
    const float* s     = (const float*)d_in[1];
    const float* te    = (const float*)d_in[2];
    const float* pmask = (const float*)d_in[3];
    const float* ipw   = (const float*)d_in[4];
    const float* ipb   = (const float*)d_in[5];
    const float* ow    = (const float*)d_in[6];
    const float* ob    = (const float*)d_in[7];
    const float* cw    = (const float*)d_in[8];
    const float* cb    = (const float*)d_in[9];

    float* out = (float*)d_out;
    const size_t NX = (size_t)MX;
    float* q_o    = out;
    float* k_o    = q_o  + NX * Ee;
    float* v_o    = k_o  + NX * Ee;
    float* out_o  = v_o  + NX * Ee;
    float* sq_o   = out_o + NX * Ee;
    float* sk_o   = sq_o + (size_t)MS * Ee;
    float* sv_o   = sk_o + (size_t)MS * Ee;
    float* sout_o = sv_o + (size_t)MS * Ee;

    char* wsb = (char*)d_ws;
    unsigned short* xb   = (unsigned short*)wsb;                  // 12800*768 bf16 (reused as mixb)
    unsigned short* wb   = xb + (size_t)MPAD * Ee;                // 2304*768
    unsigned short* owb  = wb + (size_t)3 * Ee * Ee;              // 768*768
    unsigned short* meansm_b = owb + (size_t)Ee * Ee;             // 128*768 bf16
    float* teq    = (float*)(meansm_b + (size_t)MS * Ee);
    float* tek    = teq + (size_t)MTE * Ee;
    float* tev    = tek + (size_t)MTE * Ee;
    float* smix   = tev + (size_t)MTE * Ee;                       // 64*16*768 f32
    unsigned short* mixb = xb;

    const long nXp = (long)MPAD * Ee;
    const long nW  = (long)3 * Ee * Ee;
    const long nOW = (long)Ee * Ee;
    const long nCvt = (nXp + nW + nOW) / 4;

    // 1. fused converts
    convert_all<<<dim3((nCvt + 255) / 256), 256, 0, stream>>>(
        x, s, te, ipw, ow, xb, wb, owb);

    // 2. Fused QKV projection for x+s+te (256-tile 16-wave, grid 50*9 = 450)
    {
        DstPtrs dp;
        dp.d[0] = q_o;  dp.d[1] = k_o;  dp.d[2] = v_o;
        dp.d[3] = sq_o; dp.d[4] = sk_o; dp.d[5] = sv_o;
        dp.d[6] = teq;  dp.d[7] = tek;  dp.d[8] = tev;
        mfma_gemm256<<<dim3((MPAD / 256) * 9), 1024, 0, stream>>>(
            xb, wb, ipb, dp, MX, MS, MTE, 9, 3);
    }

    // 3. self-attention (MFMA, 8 waves, P-in-registers) + fused s-branch
    attn_mfma<<<dim3(Bb * Tt * Hh), 512, 0, stream>>>(
        q_o, k_o, v_o, sq_o, tek, tev, pmask, mixb, smix);

    // 4. output projection (256-tile 16-wave, grid 50*3 = 150)
    {
        DstPtrs dp;
        for (int i = 0; i < 9; ++i) dp.d[i] = out_o;
        mfma_gemm256<<<dim3((MPAD / 256) * 3), 1024, 0, stream>>>(
            mixb, owb, ob, dp, MX, 0, 0, 3, 3);
    }

    // 5. conv + residual + mean over T -> bf16
    conv_mean_kernel<<<dim3((Bb * QSs * Ee + 255) / 256), 256, 0, stream>>>(
        smix, cw, cb, meansm_b);

    // 6. s_out projection (128-tile kernel, M=128, grid 6)
    {
        DstPtrs dp;
        for (int i = 0; i < 9; ++i) dp.d[i] = sout_o;
        mfma_gemm<<<dim3(6), 256, 0, stream>>>(
            meansm_b, owb, ob, dp, MS, 0, 0, 6, 6);
    }
}